// Round 9
// baseline (573.468 us; speedup 1.0000x reference)
//
#include <hip/hip_runtime.h>
#include <hip/hip_bf16.h>

typedef unsigned short u16;
typedef unsigned char u8;
typedef __bf16 bf16x8 __attribute__((ext_vector_type(8)));
typedef float f32x4 __attribute__((ext_vector_type(4)));
typedef int i32x4 __attribute__((ext_vector_type(4)));
typedef int i32x8 __attribute__((ext_vector_type(8)));

#define NTOK 32768   // B*S = 8*4096
#define DIM  512
#define KC   4096

__device__ __forceinline__ u16 f2b(float f) {
  __hip_bfloat16 h = __float2bfloat16(f);
  return *reinterpret_cast<u16*>(&h);
}

__device__ __forceinline__ void gload_lds16(const void* g, void* l) {
  __builtin_amdgcn_global_load_lds(
      (__attribute__((address_space(1))) void*)g,
      (__attribute__((address_space(3))) void*)l,
      16, 0, 0);
}

// -------- prep: X fp32 -> bf16 (for gate) + fp8 e4m3 (for argmin) ----------
__global__ void cvt_x(const float* __restrict__ in, u16* __restrict__ bf,
                      u8* __restrict__ q, int n8) {
  int i = blockIdx.x * blockDim.x + threadIdx.x;
  if (i >= n8) return;
  const float4* p = reinterpret_cast<const float4*>(in) + 2 * (size_t)i;
  float4 a = p[0], b = p[1];
  uint4 v;
  v.x = (unsigned)f2b(a.x) | ((unsigned)f2b(a.y) << 16);
  v.y = (unsigned)f2b(a.z) | ((unsigned)f2b(a.w) << 16);
  v.z = (unsigned)f2b(b.x) | ((unsigned)f2b(b.y) << 16);
  v.w = (unsigned)f2b(b.z) | ((unsigned)f2b(b.w) << 16);
  reinterpret_cast<uint4*>(bf)[i] = v;
  int u0 = __builtin_amdgcn_cvt_pk_fp8_f32(a.x, a.y, 0, false);
  u0     = __builtin_amdgcn_cvt_pk_fp8_f32(a.z, a.w, u0, true);
  int u1 = __builtin_amdgcn_cvt_pk_fp8_f32(b.x, b.y, 0, false);
  u1     = __builtin_amdgcn_cvt_pk_fp8_f32(b.z, b.w, u1, true);
  uint2 w2; w2.x = (unsigned)u0; w2.y = (unsigned)u1;
  reinterpret_cast<uint2*>(q)[i] = w2;
}

// W fp32 -> bf16 (gate GEMM)
__global__ void cvt8(const float* __restrict__ in, u16* __restrict__ out, int n8) {
  int i = blockIdx.x * blockDim.x + threadIdx.x;
  if (i >= n8) return;
  const float4* p = reinterpret_cast<const float4*>(in) + 2 * (size_t)i;
  float4 a = p[0], b = p[1];
  uint4 v;
  v.x = (unsigned)f2b(a.x) | ((unsigned)f2b(a.y) << 16);
  v.y = (unsigned)f2b(a.z) | ((unsigned)f2b(a.w) << 16);
  v.z = (unsigned)f2b(b.x) | ((unsigned)f2b(b.y) << 16);
  v.w = (unsigned)f2b(b.z) | ((unsigned)f2b(b.w) << 16);
  reinterpret_cast<uint4*>(out)[i] = v;
}

// codebook -> fp8 scaled by 4096 (values in ±1), plus exact fp32 row norms
__global__ void cvt_codebook(const float* __restrict__ cb, u8* __restrict__ cbq,
                             float* __restrict__ cnorm) {
  int k = blockIdx.x;          // 0..4095
  int t = threadIdx.x;         // 0..255, handles elems 2t, 2t+1
  float c0 = cb[(size_t)k * DIM + 2 * t];
  float c1 = cb[(size_t)k * DIM + 2 * t + 1];
  int pk = __builtin_amdgcn_cvt_pk_fp8_f32(c0 * 4096.f, c1 * 4096.f, 0, false);
  *reinterpret_cast<u16*>(cbq + (size_t)k * DIM + 2 * t) = (u16)(pk & 0xffff);
  float s = c0 * c0 + c1 * c1;
#pragma unroll
  for (int m = 1; m < 64; m <<= 1) s += __shfl_xor(s, m, 64);
  __shared__ float w4[4];
  if ((t & 63) == 0) w4[t >> 6] = s;
  __syncthreads();
  if (t == 0) cnorm[k] = w4[0] + w4[1] + w4[2] + w4[3];
}

// ------------- argmin GEMM (MX-fp8 K=128): scores = cnorm - 2 x.c ----------
// 128x128 tile, BK=128, 8 waves, wave-tile 32x64 -> acc[2][4] (32 VGPR),
// bfr[4] (32) + af (8): ~72 data regs, no spill (R7/R8 lesson: 64x64 wave-tile
// needs 128 data regs -> guaranteed spill, 52MB scratch traffic, 172us).
// mfma_scale 16x16x128 f8f6f4 unit scales (exact fp8, 2x rate; math verified
// R7/R8). 16B-granular XOR swizzle g^=row&7: 16-lane fragment reads cover all
// 32 banks 2-way (free). Counted-vmcnt(4) 2-deep pipeline.
__global__ __launch_bounds__(512, 4)
void argmin_mx(const u8* __restrict__ Xq, const u8* __restrict__ Cq,
               const float* __restrict__ cnorm,
               float* __restrict__ pval, int* __restrict__ pidx) {
  __shared__ u8 As[2][128 * 128];   // 16 KiB each
  __shared__ u8 Bs[2][128 * 128];   // 16 KiB each  (64 KiB total)

  const int tid  = threadIdx.x;
  const int lane = tid & 63;
  const int wid  = tid >> 6;          // 0..7
  const int wr   = wid >> 1;          // 0..3 (M quarter: 32 rows)
  const int wc   = wid & 1;           // 0..1 (N half: 64 cols)
  const int bm   = blockIdx.x;        // 0..255 token tiles (128 each)
  const int bn   = blockIdx.y;        // 0..31  code tiles (128 each)
  const int l15  = lane & 15, l4 = lane >> 4;
  const int srow8 = lane >> 3;        // 0..7 row within staged 8-row chunk
  const int sg    = lane & 7;         // 16B granule slot within 128B row

  const u8* Xg = Xq + (size_t)(bm * 128) * DIM;
  const u8* Cg = Cq + (size_t)(bn * 128) * DIM;

  // stage one K-tile: A 128x128B + B 128x128B, 16 chunks each (8 rows x 128B),
  // one chunk per wave per pass -> 4 gload_lds per thread per tile.
  // Source granule pre-swizzled: phys = g ^ (row&7) (involution).
  auto stage = [&](int buf, int kt) {
    int kk = kt * 128;
#pragma unroll
    for (int p = 0; p < 2; p++) {
      int chunk = p * 8 + wid;                 // 0..15
      int row = chunk * 8 + srow8;             // 0..127
      int phys = sg ^ (row & 7);
      gload_lds16(Xg + (size_t)row * DIM + kk + phys * 16,
                  (void*)(As[buf] + chunk * 1024));
    }
#pragma unroll
    for (int p = 0; p < 2; p++) {
      int chunk = p * 8 + wid;
      int row = chunk * 8 + srow8;
      int phys = sg ^ (row & 7);
      gload_lds16(Cg + (size_t)row * DIM + kk + phys * 16,
                  (void*)(Bs[buf] + chunk * 1024));
    }
  };

  // swizzled 32B fragment read (lane's K-block l4 of row) as two b128 reads
  auto rd32 = [&](const u8* base, int row) -> i32x8 {
    const u8* p0 = base + row * 128 + ((2 * l4 + 0) ^ (row & 7)) * 16;
    const u8* p1 = base + row * 128 + ((2 * l4 + 1) ^ (row & 7)) * 16;
    i32x4 lo = *reinterpret_cast<const i32x4*>(p0);
    i32x4 hi = *reinterpret_cast<const i32x4*>(p1);
    i32x8 r;
#pragma unroll
    for (int i = 0; i < 4; i++) { r[i] = lo[i]; r[i + 4] = hi[i]; }
    return r;
  };

  f32x4 acc[2][4];
#pragma unroll
  for (int i = 0; i < 2; i++)
#pragma unroll
    for (int j = 0; j < 4; j++)
#pragma unroll
      for (int r = 0; r < 4; r++) acc[i][j][r] = 0.f;

  stage(0, 0);
  stage(1, 1);
  asm volatile("s_waitcnt vmcnt(4)" ::: "memory");   // tile0's 4 landed
  __builtin_amdgcn_s_barrier();
  asm volatile("" ::: "memory");

  for (int t = 0; t < 4; ++t) {
    const u8* A  = As[t & 1];
    const u8* Bt = Bs[t & 1];
    i32x8 bfr[4];
#pragma unroll
    for (int ni = 0; ni < 4; ni++) bfr[ni] = rd32(Bt, wc * 64 + ni * 16 + l15);
#pragma unroll
    for (int mi = 0; mi < 2; mi++) {
      i32x8 af = rd32(A, wr * 32 + mi * 16 + l15);
      __builtin_amdgcn_s_setprio(1);
#pragma unroll
      for (int ni = 0; ni < 4; ni++)
        acc[mi][ni] = __builtin_amdgcn_mfma_scale_f32_16x16x128_f8f6f4(
            af, bfr[ni], acc[mi][ni],
            0, 0,                     // fp8 e4m3 / fp8 e4m3
            0, 0x7f7f7f7f,            // A scales = 1.0 (E8M0 127)
            0, 0x7f7f7f7f);           // B scales = 1.0
      __builtin_amdgcn_s_setprio(0);
    }

    asm volatile("" ::: "memory");
    __builtin_amdgcn_s_barrier();          // all waves done reading buf[t&1]
    asm volatile("" ::: "memory");
    if (t + 2 < 4) {
      stage(t & 1, t + 2);                 // refill freed buffer (4 loads)
      asm volatile("s_waitcnt vmcnt(4)" ::: "memory");   // tile t+1 landed
      __builtin_amdgcn_s_barrier();
      asm volatile("" ::: "memory");
    } else if (t < 3) {
      asm volatile("s_waitcnt vmcnt(0)" ::: "memory");
      __builtin_amdgcn_s_barrier();
      asm volatile("" ::: "memory");
    }
  }

  // -------- epilogue: per-token argmin over this block's 128 codes ---------
  // scores = cnorm - (2/4096) * acc   (codebook was pre-scaled by 4096)
  const float SC = 4.8828125e-4f;   // 2^-11
  float* rv = (float*)As;   // [2][128] — alias, safe after final barrier
  int*   ri = (int*)Bs;
  __syncthreads();

#pragma unroll
  for (int mi = 0; mi < 2; mi++) {
#pragma unroll
    for (int r = 0; r < 4; r++) {
      float best = 1e30f;
      int bi = 0;
#pragma unroll
      for (int ni = 0; ni < 4; ni++) {
        int code = bn * 128 + wc * 64 + ni * 16 + l15;
        float v = cnorm[code] - SC * acc[mi][ni][r];
        if (v < best) { best = v; bi = code; }
      }
#pragma unroll
      for (int m = 1; m < 16; m <<= 1) {
        float ov = __shfl_xor(best, m, 64);
        int   oi = __shfl_xor(bi, m, 64);
        if (ov < best) { best = ov; bi = oi; }
      }
      if (l15 == 0) {
        int tok = wr * 32 + mi * 16 + l4 * 4 + r;   // 0..127
        rv[wc * 128 + tok] = best;
        ri[wc * 128 + tok] = bi;
      }
    }
  }
  __syncthreads();
  if (tid < 128) {
    float bv = rv[tid];
    int   bb = ri[tid];
    float v1 = rv[128 + tid];
    if (v1 < bv) { bv = v1; bb = ri[128 + tid]; }
    size_t g = (size_t)bn * NTOK + bm * 128 + tid;
    pval[g] = bv;
    pidx[g] = bb;
  }
}

__global__ void argmin_reduce(const float* __restrict__ pval, const int* __restrict__ pidx,
                              int* __restrict__ idx) {
  int t = blockIdx.x * 256 + threadIdx.x;   // 0..32767
  float best = 1e30f;
  int bi = 0;
  for (int c = 0; c < 32; c++) {
    float v = pval[(size_t)c * NTOK + t];
    if (v < best) { best = v; bi = pidx[(size_t)c * NTOK + t]; }
  }
  idx[t] = bi;
}

// ---------- gate GEMM (X @ W^T) + fused epilogue + deterministic loss -------
__global__ __launch_bounds__(256)
void gate_out(const u16* __restrict__ Xb, const u16* __restrict__ Wb,
              const float* __restrict__ X, const float* __restrict__ Cf,
              const float* __restrict__ gb, const int* __restrict__ idx,
              float* __restrict__ out, float* __restrict__ blockSum) {
  __shared__ u16 As[2][128 * 64];
  __shared__ u16 Bs[2][128 * 64];
  __shared__ float bsum[4];

  const int tid  = threadIdx.x;
  const int lane = tid & 63;
  const int wid  = tid >> 6;
  const int wr   = wid >> 1, wc = wid & 1;
  const int bm   = blockIdx.x;        // 0..255
  const int bn   = blockIdx.y;        // 0..3
  const int l15  = lane & 15, l4 = lane >> 4;
  const int srow = lane >> 3;
  const int scol = (((lane & 7) ^ (lane >> 3)) & 7) * 8;

  const u16* Xrow = Xb + (size_t)(bm * 128) * DIM;
  const u16* Wrow = Wb + (size_t)(bn * 128) * DIM;

  auto stage = [&](int buf, int kk) {
#pragma unroll
    for (int i = 0; i < 4; i++) {
      int rA = (wid * 4 + i) * 8 + srow;
      gload_lds16(Xrow + (size_t)rA * DIM + kk + scol,
                  (void*)(As[buf] + (wid * 4 + i) * 512));
      gload_lds16(Wrow + (size_t)rA * DIM + kk + scol,
                  (void*)(Bs[buf] + (wid * 4 + i) * 512));
    }
  };

  f32x4 acc[4][4];
#pragma unroll
  for (int i = 0; i < 4; i++)
#pragma unroll
    for (int j = 0; j < 4; j++)
#pragma unroll
      for (int r = 0; r < 4; r++) acc[i][j][r] = 0.f;

  stage(0, 0);
  __syncthreads();
  int cur = 0;
  for (int t = 0; t < 8; ++t) {
    if (t < 7) stage(cur ^ 1, (t + 1) * 64);
#pragma unroll
    for (int ks = 0; ks < 2; ks++) {
      bf16x8 af[4], bfr[4];
#pragma unroll
      for (int mi = 0; mi < 4; mi++) {
        int row = wr * 64 + mi * 16 + l15;
        int col = (ks * 32 + l4 * 8) ^ ((row & 7) << 3);
        af[mi] = *reinterpret_cast<const bf16x8*>(As[cur] + row * 64 + col);
      }
#pragma unroll
      for (int ni = 0; ni < 4; ni++) {
        int row = wc * 64 + ni * 16 + l15;
        int col = (ks * 32 + l4 * 8) ^ ((row & 7) << 3);
        bfr[ni] = *reinterpret_cast<const bf16x8*>(Bs[cur] + row * 64 + col);
      }
#pragma unroll
      for (int mi = 0; mi < 4; mi++)
#pragma unroll
        for (int ni = 0; ni < 4; ni++)
          acc[mi][ni] = __builtin_amdgcn_mfma_f32_16x16x32_bf16(
              af[mi], bfr[ni], acc[mi][ni], 0, 0, 0);
    }
    __syncthreads();
    cur ^= 1;
  }

  // epilogue: gate = sigmoid(acc + b), out = x + c[idx]*gate, loss partial
  float lsum = 0.f;
#pragma unroll
  for (int mi = 0; mi < 4; mi++) {
#pragma unroll
    for (int r = 0; r < 4; r++) {
      int token = bm * 128 + wr * 64 + mi * 16 + l4 * 4 + r;
      int code = idx[token];
#pragma unroll
      for (int ni = 0; ni < 4; ni++) {
        int col = bn * 128 + wc * 64 + ni * 16 + l15;
        float logit = acc[mi][ni][r] + gb[col];
        float g = 1.0f / (1.0f + __expf(-logit));
        float q = Cf[(size_t)code * DIM + col];
        float xx = X[(size_t)token * DIM + col];
        out[(size_t)token * DIM + col] = xx + q * g;
        float d = q - xx;
        lsum += d * d;
      }
    }
  }
#pragma unroll
  for (int m = 1; m < 64; m <<= 1) lsum += __shfl_xor(lsum, m, 64);
  if (lane == 0) bsum[wid] = lsum;
  __syncthreads();
  if (tid == 0)
    blockSum[blockIdx.y * gridDim.x + blockIdx.x] = bsum[0] + bsum[1] + bsum[2] + bsum[3];
}

__global__ void finalize(const float* __restrict__ blockSum, float* __restrict__ out_loss) {
  int t = threadIdx.x;  // 256 threads, 1024 partials
  float s = 0.f;
#pragma unroll
  for (int i = 0; i < 4; i++) s += blockSum[t * 4 + i];
#pragma unroll
  for (int m = 1; m < 64; m <<= 1) s += __shfl_xor(s, m, 64);
  __shared__ float w4[4];
  if ((t & 63) == 0) w4[t >> 6] = s;
  __syncthreads();
  if (t == 0) {
    float tot = w4[0] + w4[1] + w4[2] + w4[3];
    out_loss[0] = 1.25f * tot / 16777216.0f;   // N*D = 32768*512
  }
}

extern "C" void kernel_launch(void* const* d_in, const int* in_sizes, int n_in,
                              void* d_out, int out_size, void* d_ws, size_t ws_size,
                              hipStream_t stream) {
  const float* X  = (const float*)d_in[0];   // [32768, 512]
  const float* CB = (const float*)d_in[1];   // [4096, 512]
  const float* GW = (const float*)d_in[2];   // [512, 512]
  const float* GB = (const float*)d_in[3];   // [512]
  float* out = (float*)d_out;                // [32768*512] output + [1] loss

  char* w = (char*)d_ws;
  size_t off = 0;
  auto alloc = [&](size_t bytes) -> void* {
    void* p = w + off;
    off = (off + bytes + 255) & ~(size_t)255;
    return p;
  };
  u16*   Xb    = (u16*)alloc((size_t)NTOK * DIM * 2);   // 33.5 MB (gate)
  u8*    Xq    = (u8*) alloc((size_t)NTOK * DIM);       // 16.8 MB (argmin)
  u8*    Cq    = (u8*) alloc((size_t)KC * DIM);         // 2.1 MB (argmin, x4096)
  u16*   Wb    = (u16*)alloc((size_t)DIM * DIM * 2);    // 0.5 MB
  float* cnorm = (float*)alloc((size_t)KC * 4);
  float* pval  = (float*)alloc((size_t)32 * NTOK * 4);  // 4.2 MB
  int*   pidx  = (int*)alloc((size_t)32 * NTOK * 4);    // 4.2 MB
  int*   idx   = (int*)alloc((size_t)NTOK * 4);
  float* bsums = (float*)alloc((size_t)1024 * 4);

  cvt_x<<<8192, 256, 0, stream>>>(X, Xb, Xq, NTOK * DIM / 8);
  cvt8<<<128, 256, 0, stream>>>(GW, Wb, DIM * DIM / 8);
  cvt_codebook<<<KC, 256, 0, stream>>>(CB, Cq, cnorm);
  argmin_mx<<<dim3(256, 32), 512, 0, stream>>>(Xq, Cq, cnorm, pval, pidx);
  argmin_reduce<<<128, 256, 0, stream>>>(pval, pidx, idx);
  gate_out<<<dim3(256, 4), 256, 0, stream>>>(Xb, Wb, X, CB, GB, idx, out, bsums);
  finalize<<<1, 256, 0, stream>>>(bsums, out + (size_t)NTOK * DIM);
}

// Round 10
// 279.610 us; speedup vs baseline: 2.0510x; 2.0510x over previous
//
#include <hip/hip_runtime.h>
#include <hip/hip_bf16.h>

typedef unsigned short u16;
typedef unsigned char u8;
typedef __bf16 bf16x8 __attribute__((ext_vector_type(8)));
typedef float f32x4 __attribute__((ext_vector_type(4)));
typedef int i32x4 __attribute__((ext_vector_type(4)));
typedef int i32x8 __attribute__((ext_vector_type(8)));

#define NTOK 32768   // B*S = 8*4096
#define DIM  512
#define KC   4096

__device__ __forceinline__ u16 f2b(float f) {
  __hip_bfloat16 h = __float2bfloat16(f);
  return *reinterpret_cast<u16*>(&h);
}

__device__ __forceinline__ void gload_lds16(const void* g, void* l) {
  __builtin_amdgcn_global_load_lds(
      (__attribute__((address_space(1))) void*)g,
      (__attribute__((address_space(3))) void*)l,
      16, 0, 0);
}

// -------- prep: X fp32 -> bf16 (for gate) + fp8 e4m3 (for argmin) ----------
__global__ void cvt_x(const float* __restrict__ in, u16* __restrict__ bf,
                      u8* __restrict__ q, int n8) {
  int i = blockIdx.x * blockDim.x + threadIdx.x;
  if (i >= n8) return;
  const float4* p = reinterpret_cast<const float4*>(in) + 2 * (size_t)i;
  float4 a = p[0], b = p[1];
  uint4 v;
  v.x = (unsigned)f2b(a.x) | ((unsigned)f2b(a.y) << 16);
  v.y = (unsigned)f2b(a.z) | ((unsigned)f2b(a.w) << 16);
  v.z = (unsigned)f2b(b.x) | ((unsigned)f2b(b.y) << 16);
  v.w = (unsigned)f2b(b.z) | ((unsigned)f2b(b.w) << 16);
  reinterpret_cast<uint4*>(bf)[i] = v;
  int u0 = __builtin_amdgcn_cvt_pk_fp8_f32(a.x, a.y, 0, false);
  u0     = __builtin_amdgcn_cvt_pk_fp8_f32(a.z, a.w, u0, true);
  int u1 = __builtin_amdgcn_cvt_pk_fp8_f32(b.x, b.y, 0, false);
  u1     = __builtin_amdgcn_cvt_pk_fp8_f32(b.z, b.w, u1, true);
  uint2 w2; w2.x = (unsigned)u0; w2.y = (unsigned)u1;
  reinterpret_cast<uint2*>(q)[i] = w2;
}

// W fp32 -> bf16 (gate GEMM)
__global__ void cvt8(const float* __restrict__ in, u16* __restrict__ out, int n8) {
  int i = blockIdx.x * blockDim.x + threadIdx.x;
  if (i >= n8) return;
  const float4* p = reinterpret_cast<const float4*>(in) + 2 * (size_t)i;
  float4 a = p[0], b = p[1];
  uint4 v;
  v.x = (unsigned)f2b(a.x) | ((unsigned)f2b(a.y) << 16);
  v.y = (unsigned)f2b(a.z) | ((unsigned)f2b(a.w) << 16);
  v.z = (unsigned)f2b(b.x) | ((unsigned)f2b(b.y) << 16);
  v.w = (unsigned)f2b(b.z) | ((unsigned)f2b(b.w) << 16);
  reinterpret_cast<uint4*>(out)[i] = v;
}

// codebook -> fp8 scaled by 4096 (values in ±1), plus exact fp32 row norms
__global__ void cvt_codebook(const float* __restrict__ cb, u8* __restrict__ cbq,
                             float* __restrict__ cnorm) {
  int k = blockIdx.x;          // 0..4095
  int t = threadIdx.x;         // 0..255, handles elems 2t, 2t+1
  float c0 = cb[(size_t)k * DIM + 2 * t];
  float c1 = cb[(size_t)k * DIM + 2 * t + 1];
  int pk = __builtin_amdgcn_cvt_pk_fp8_f32(c0 * 4096.f, c1 * 4096.f, 0, false);
  *reinterpret_cast<u16*>(cbq + (size_t)k * DIM + 2 * t) = (u16)(pk & 0xffff);
  float s = c0 * c0 + c1 * c1;
#pragma unroll
  for (int m = 1; m < 64; m <<= 1) s += __shfl_xor(s, m, 64);
  __shared__ float w4[4];
  if ((t & 63) == 0) w4[t >> 6] = s;
  __syncthreads();
  if (t == 0) cnorm[k] = w4[0] + w4[1] + w4[2] + w4[3];
}

// ------------- argmin GEMM (MX-fp8 K=128): scores = cnorm - 2 x.c ----------
// 128x128 tile, BK=128, 8 waves, wave-tile 32x64 -> acc[2][4] (32 AGPR),
// bfr[4] (32 VGPR) + af (8). R9 ERRATA: __launch_bounds__(512,4) forced a
// 128-combined reg cap -> VGPR pinned at 64 -> 1.19 GB spill traffic, 488us.
// Fix: (512,2) gives the allocator a 256-combined budget (R4 precedent:
// VGPR=120, zero spill at same bound).
__global__ __launch_bounds__(512, 2)
void argmin_mx(const u8* __restrict__ Xq, const u8* __restrict__ Cq,
               const float* __restrict__ cnorm,
               float* __restrict__ pval, int* __restrict__ pidx) {
  __shared__ u8 As[2][128 * 128];   // 16 KiB each
  __shared__ u8 Bs[2][128 * 128];   // 16 KiB each  (64 KiB total)

  const int tid  = threadIdx.x;
  const int lane = tid & 63;
  const int wid  = tid >> 6;          // 0..7
  const int wr   = wid >> 1;          // 0..3 (M quarter: 32 rows)
  const int wc   = wid & 1;           // 0..1 (N half: 64 cols)
  const int bm   = blockIdx.x;        // 0..255 token tiles (128 each)
  const int bn   = blockIdx.y;        // 0..31  code tiles (128 each)
  const int l15  = lane & 15, l4 = lane >> 4;
  const int srow8 = lane >> 3;        // 0..7 row within staged 8-row chunk
  const int sg    = lane & 7;         // 16B granule slot within 128B row

  const u8* Xg = Xq + (size_t)(bm * 128) * DIM;
  const u8* Cg = Cq + (size_t)(bn * 128) * DIM;

  // stage one K-tile: A 128x128B + B 128x128B, 16 chunks each (8 rows x 128B),
  // one chunk per wave per pass -> 4 gload_lds per thread per tile.
  // Source granule pre-swizzled: phys = g ^ (row&7) (involution).
  auto stage = [&](int buf, int kt) {
    int kk = kt * 128;
#pragma unroll
    for (int p = 0; p < 2; p++) {
      int chunk = p * 8 + wid;                 // 0..15
      int row = chunk * 8 + srow8;             // 0..127
      int phys = sg ^ (row & 7);
      gload_lds16(Xg + (size_t)row * DIM + kk + phys * 16,
                  (void*)(As[buf] + chunk * 1024));
    }
#pragma unroll
    for (int p = 0; p < 2; p++) {
      int chunk = p * 8 + wid;
      int row = chunk * 8 + srow8;
      int phys = sg ^ (row & 7);
      gload_lds16(Cg + (size_t)row * DIM + kk + phys * 16,
                  (void*)(Bs[buf] + chunk * 1024));
    }
  };

  // swizzled 32B fragment read (lane's K-block l4 of row) as two b128 reads
  auto rd32 = [&](const u8* base, int row) -> i32x8 {
    const u8* p0 = base + row * 128 + ((2 * l4 + 0) ^ (row & 7)) * 16;
    const u8* p1 = base + row * 128 + ((2 * l4 + 1) ^ (row & 7)) * 16;
    i32x4 lo = *reinterpret_cast<const i32x4*>(p0);
    i32x4 hi = *reinterpret_cast<const i32x4*>(p1);
    i32x8 r;
#pragma unroll
    for (int i = 0; i < 4; i++) { r[i] = lo[i]; r[i + 4] = hi[i]; }
    return r;
  };

  f32x4 acc[2][4];
#pragma unroll
  for (int i = 0; i < 2; i++)
#pragma unroll
    for (int j = 0; j < 4; j++)
#pragma unroll
      for (int r = 0; r < 4; r++) acc[i][j][r] = 0.f;

  stage(0, 0);
  stage(1, 1);
  asm volatile("s_waitcnt vmcnt(4)" ::: "memory");   // tile0's 4 landed
  __builtin_amdgcn_s_barrier();
  asm volatile("" ::: "memory");

  for (int t = 0; t < 4; ++t) {
    const u8* A  = As[t & 1];
    const u8* Bt = Bs[t & 1];
    i32x8 bfr[4];
#pragma unroll
    for (int ni = 0; ni < 4; ni++) bfr[ni] = rd32(Bt, wc * 64 + ni * 16 + l15);
#pragma unroll
    for (int mi = 0; mi < 2; mi++) {
      i32x8 af = rd32(A, wr * 32 + mi * 16 + l15);
      __builtin_amdgcn_s_setprio(1);
#pragma unroll
      for (int ni = 0; ni < 4; ni++)
        acc[mi][ni] = __builtin_amdgcn_mfma_scale_f32_16x16x128_f8f6f4(
            af, bfr[ni], acc[mi][ni],
            0, 0,                     // fp8 e4m3 / fp8 e4m3
            0, 0x7f7f7f7f,            // A scales = 1.0 (E8M0 127)
            0, 0x7f7f7f7f);           // B scales = 1.0
      __builtin_amdgcn_s_setprio(0);
    }

    asm volatile("" ::: "memory");
    __builtin_amdgcn_s_barrier();          // all waves done reading buf[t&1]
    asm volatile("" ::: "memory");
    if (t + 2 < 4) {
      stage(t & 1, t + 2);                 // refill freed buffer (4 loads)
      asm volatile("s_waitcnt vmcnt(4)" ::: "memory");   // tile t+1 landed
      __builtin_amdgcn_s_barrier();
      asm volatile("" ::: "memory");
    } else if (t < 3) {
      asm volatile("s_waitcnt vmcnt(0)" ::: "memory");
      __builtin_amdgcn_s_barrier();
      asm volatile("" ::: "memory");
    }
  }

  // -------- epilogue: per-token argmin over this block's 128 codes ---------
  // scores = cnorm - (2/4096) * acc   (codebook was pre-scaled by 4096)
  const float SC = 4.8828125e-4f;   // 2^-11
  float* rv = (float*)As;   // [2][128] — alias, safe after final barrier
  int*   ri = (int*)Bs;
  __syncthreads();

#pragma unroll
  for (int mi = 0; mi < 2; mi++) {
#pragma unroll
    for (int r = 0; r < 4; r++) {
      float best = 1e30f;
      int bi = 0;
#pragma unroll
      for (int ni = 0; ni < 4; ni++) {
        int code = bn * 128 + wc * 64 + ni * 16 + l15;
        float v = cnorm[code] - SC * acc[mi][ni][r];
        if (v < best) { best = v; bi = code; }
      }
#pragma unroll
      for (int m = 1; m < 16; m <<= 1) {
        float ov = __shfl_xor(best, m, 64);
        int   oi = __shfl_xor(bi, m, 64);
        if (ov < best) { best = ov; bi = oi; }
      }
      if (l15 == 0) {
        int tok = wr * 32 + mi * 16 + l4 * 4 + r;   // 0..127
        rv[wc * 128 + tok] = best;
        ri[wc * 128 + tok] = bi;
      }
    }
  }
  __syncthreads();
  if (tid < 128) {
    float bv = rv[tid];
    int   bb = ri[tid];
    float v1 = rv[128 + tid];
    if (v1 < bv) { bv = v1; bb = ri[128 + tid]; }
    size_t g = (size_t)bn * NTOK + bm * 128 + tid;
    pval[g] = bv;
    pidx[g] = bb;
  }
}

__global__ void argmin_reduce(const float* __restrict__ pval, const int* __restrict__ pidx,
                              int* __restrict__ idx) {
  int t = blockIdx.x * 256 + threadIdx.x;   // 0..32767
  float best = 1e30f;
  int bi = 0;
  for (int c = 0; c < 32; c++) {
    float v = pval[(size_t)c * NTOK + t];
    if (v < best) { best = v; bi = pidx[(size_t)c * NTOK + t]; }
  }
  idx[t] = bi;
}

// ---------- gate GEMM (X @ W^T) + fused epilogue + deterministic loss -------
__global__ __launch_bounds__(256)
void gate_out(const u16* __restrict__ Xb, const u16* __restrict__ Wb,
              const float* __restrict__ X, const float* __restrict__ Cf,
              const float* __restrict__ gb, const int* __restrict__ idx,
              float* __restrict__ out, float* __restrict__ blockSum) {
  __shared__ u16 As[2][128 * 64];
  __shared__ u16 Bs[2][128 * 64];
  __shared__ float bsum[4];

  const int tid  = threadIdx.x;
  const int lane = tid & 63;
  const int wid  = tid >> 6;
  const int wr   = wid >> 1, wc = wid & 1;
  const int bm   = blockIdx.x;        // 0..255
  const int bn   = blockIdx.y;        // 0..3
  const int l15  = lane & 15, l4 = lane >> 4;
  const int srow = lane >> 3;
  const int scol = (((lane & 7) ^ (lane >> 3)) & 7) * 8;

  const u16* Xrow = Xb + (size_t)(bm * 128) * DIM;
  const u16* Wrow = Wb + (size_t)(bn * 128) * DIM;

  auto stage = [&](int buf, int kk) {
#pragma unroll
    for (int i = 0; i < 4; i++) {
      int rA = (wid * 4 + i) * 8 + srow;
      gload_lds16(Xrow + (size_t)rA * DIM + kk + scol,
                  (void*)(As[buf] + (wid * 4 + i) * 512));
      gload_lds16(Wrow + (size_t)rA * DIM + kk + scol,
                  (void*)(Bs[buf] + (wid * 4 + i) * 512));
    }
  };

  f32x4 acc[4][4];
#pragma unroll
  for (int i = 0; i < 4; i++)
#pragma unroll
    for (int j = 0; j < 4; j++)
#pragma unroll
      for (int r = 0; r < 4; r++) acc[i][j][r] = 0.f;

  stage(0, 0);
  __syncthreads();
  int cur = 0;
  for (int t = 0; t < 8; ++t) {
    if (t < 7) stage(cur ^ 1, (t + 1) * 64);
#pragma unroll
    for (int ks = 0; ks < 2; ks++) {
      bf16x8 af[4], bfr[4];
#pragma unroll
      for (int mi = 0; mi < 4; mi++) {
        int row = wr * 64 + mi * 16 + l15;
        int col = (ks * 32 + l4 * 8) ^ ((row & 7) << 3);
        af[mi] = *reinterpret_cast<const bf16x8*>(As[cur] + row * 64 + col);
      }
#pragma unroll
      for (int ni = 0; ni < 4; ni++) {
        int row = wc * 64 + ni * 16 + l15;
        int col = (ks * 32 + l4 * 8) ^ ((row & 7) << 3);
        bfr[ni] = *reinterpret_cast<const bf16x8*>(Bs[cur] + row * 64 + col);
      }
#pragma unroll
      for (int mi = 0; mi < 4; mi++)
#pragma unroll
        for (int ni = 0; ni < 4; ni++)
          acc[mi][ni] = __builtin_amdgcn_mfma_f32_16x16x32_bf16(
              af[mi], bfr[ni], acc[mi][ni], 0, 0, 0);
    }
    __syncthreads();
    cur ^= 1;
  }

  // epilogue: gate = sigmoid(acc + b), out = x + c[idx]*gate, loss partial
  float lsum = 0.f;
#pragma unroll
  for (int mi = 0; mi < 4; mi++) {
#pragma unroll
    for (int r = 0; r < 4; r++) {
      int token = bm * 128 + wr * 64 + mi * 16 + l4 * 4 + r;
      int code = idx[token];
#pragma unroll
      for (int ni = 0; ni < 4; ni++) {
        int col = bn * 128 + wc * 64 + ni * 16 + l15;
        float logit = acc[mi][ni][r] + gb[col];
        float g = 1.0f / (1.0f + __expf(-logit));
        float q = Cf[(size_t)code * DIM + col];
        float xx = X[(size_t)token * DIM + col];
        out[(size_t)token * DIM + col] = xx + q * g;
        float d = q - xx;
        lsum += d * d;
      }
    }
  }
#pragma unroll
  for (int m = 1; m < 64; m <<= 1) lsum += __shfl_xor(lsum, m, 64);
  if (lane == 0) bsum[wid] = lsum;
  __syncthreads();
  if (tid == 0)
    blockSum[blockIdx.y * gridDim.x + blockIdx.x] = bsum[0] + bsum[1] + bsum[2] + bsum[3];
}

__global__ void finalize(const float* __restrict__ blockSum, float* __restrict__ out_loss) {
  int t = threadIdx.x;  // 256 threads, 1024 partials
  float s = 0.f;
#pragma unroll
  for (int i = 0; i < 4; i++) s += blockSum[t * 4 + i];
#pragma unroll
  for (int m = 1; m < 64; m <<= 1) s += __shfl_xor(s, m, 64);
  __shared__ float w4[4];
  if ((t & 63) == 0) w4[t >> 6] = s;
  __syncthreads();
  if (t == 0) {
    float tot = w4[0] + w4[1] + w4[2] + w4[3];
    out_loss[0] = 1.25f * tot / 16777216.0f;   // N*D = 32768*512
  }
}

extern "C" void kernel_launch(void* const* d_in, const int* in_sizes, int n_in,
                              void* d_out, int out_size, void* d_ws, size_t ws_size,
                              hipStream_t stream) {
  const float* X  = (const float*)d_in[0];   // [32768, 512]
  const float* CB = (const float*)d_in[1];   // [4096, 512]
  const float* GW = (const float*)d_in[2];   // [512, 512]
  const float* GB = (const float*)d_in[3];   // [512]
  float* out = (float*)d_out;                // [32768*512] output + [1] loss

  char* w = (char*)d_ws;
  size_t off = 0;
  auto alloc = [&](size_t bytes) -> void* {
    void* p = w + off;
    off = (off + bytes + 255) & ~(size_t)255;
    return p;
  };
  u16*   Xb    = (u16*)alloc((size_t)NTOK * DIM * 2);   // 33.5 MB (gate)
  u8*    Xq    = (u8*) alloc((size_t)NTOK * DIM);       // 16.8 MB (argmin)
  u8*    Cq    = (u8*) alloc((size_t)KC * DIM);         // 2.1 MB (argmin, x4096)
  u16*   Wb    = (u16*)alloc((size_t)DIM * DIM * 2);    // 0.5 MB
  float* cnorm = (float*)alloc((size_t)KC * 4);
  float* pval  = (float*)alloc((size_t)32 * NTOK * 4);  // 4.2 MB
  int*   pidx  = (int*)alloc((size_t)32 * NTOK * 4);    // 4.2 MB
  int*   idx   = (int*)alloc((size_t)NTOK * 4);
  float* bsums = (float*)alloc((size_t)1024 * 4);

  cvt_x<<<8192, 256, 0, stream>>>(X, Xb, Xq, NTOK * DIM / 8);
  cvt8<<<128, 256, 0, stream>>>(GW, Wb, DIM * DIM / 8);
  cvt_codebook<<<KC, 256, 0, stream>>>(CB, Cq, cnorm);
  argmin_mx<<<dim3(256, 32), 512, 0, stream>>>(Xq, Cq, cnorm, pval, pidx);
  argmin_reduce<<<128, 256, 0, stream>>>(pval, pidx, idx);
  gate_out<<<dim3(256, 4), 256, 0, stream>>>(Xb, Wb, X, CB, GB, idx, out, bsums);
  finalize<<<1, 256, 0, stream>>>(bsums, out + (size_t)NTOK * DIM);
}

// Round 11
// 224.868 us; speedup vs baseline: 2.5502x; 1.2434x over previous
//
#include <hip/hip_runtime.h>
#include <hip/hip_bf16.h>

typedef unsigned short u16;
typedef unsigned char u8;
typedef __bf16 bf16x8 __attribute__((ext_vector_type(8)));
typedef float f32x4 __attribute__((ext_vector_type(4)));

#define NTOK 32768   // B*S = 8*4096
#define DIM  512
#define KC   4096

__device__ __forceinline__ u16 f2b(float f) {
  __hip_bfloat16 h = __float2bfloat16(f);
  return *reinterpret_cast<u16*>(&h);
}

__device__ __forceinline__ void gload_lds16(const void* g, void* l) {
  __builtin_amdgcn_global_load_lds(
      (__attribute__((address_space(1))) void*)g,
      (__attribute__((address_space(3))) void*)l,
      16, 0, 0);
}

// -------- prep: X fp32 -> bf16 (for gate) + fp8 e4m3 (for argmin) ----------
// Xq is written in a SWIZZLED layout: within each 64B K-chunk of each row,
// 8B block s8 lives at phys = s8 ^ ((row>>1)&7). This makes argmin's
// ds_read_b64 fragment reads perfectly bank-balanced (R6's 2-bit 16B swizzle
// left 4-way conflicts, 1.26e7 cycles).
__global__ void cvt_x(const float* __restrict__ in, u16* __restrict__ bf,
                      u8* __restrict__ q, int n8) {
  int i = blockIdx.x * blockDim.x + threadIdx.x;
  if (i >= n8) return;
  const float4* p = reinterpret_cast<const float4*>(in) + 2 * (size_t)i;
  float4 a = p[0], b = p[1];
  uint4 v;
  v.x = (unsigned)f2b(a.x) | ((unsigned)f2b(a.y) << 16);
  v.y = (unsigned)f2b(a.z) | ((unsigned)f2b(a.w) << 16);
  v.z = (unsigned)f2b(b.x) | ((unsigned)f2b(b.y) << 16);
  v.w = (unsigned)f2b(b.z) | ((unsigned)f2b(b.w) << 16);
  reinterpret_cast<uint4*>(bf)[i] = v;
  int u0 = __builtin_amdgcn_cvt_pk_fp8_f32(a.x, a.y, 0, false);
  u0     = __builtin_amdgcn_cvt_pk_fp8_f32(a.z, a.w, u0, true);
  int u1 = __builtin_amdgcn_cvt_pk_fp8_f32(b.x, b.y, 0, false);
  u1     = __builtin_amdgcn_cvt_pk_fp8_f32(b.z, b.w, u1, true);
  uint2 w2; w2.x = (unsigned)u0; w2.y = (unsigned)u1;
  int row   = i >> 6;            // i indexes 8B blocks; 64 per row
  int s8l   = i & 63;            // linear 8B slot in row
  int chunk = s8l >> 3;          // 64B K-chunk 0..7
  int s8in  = s8l & 7;
  int h     = (row >> 1) & 7;
  size_t dst = (size_t)row * 512 + chunk * 64 + (size_t)(s8in ^ h) * 8;
  *reinterpret_cast<uint2*>(q + dst) = w2;
}

// W fp32 -> bf16 (gate GEMM)
__global__ void cvt8(const float* __restrict__ in, u16* __restrict__ out, int n8) {
  int i = blockIdx.x * blockDim.x + threadIdx.x;
  if (i >= n8) return;
  const float4* p = reinterpret_cast<const float4*>(in) + 2 * (size_t)i;
  float4 a = p[0], b = p[1];
  uint4 v;
  v.x = (unsigned)f2b(a.x) | ((unsigned)f2b(a.y) << 16);
  v.y = (unsigned)f2b(a.z) | ((unsigned)f2b(a.w) << 16);
  v.z = (unsigned)f2b(b.x) | ((unsigned)f2b(b.y) << 16);
  v.w = (unsigned)f2b(b.z) | ((unsigned)f2b(b.w) << 16);
  reinterpret_cast<uint4*>(out)[i] = v;
}

// codebook -> fp8 scaled by 4096 (values in ±1), SAME swizzled layout as Xq,
// plus exact fp32 row norms
__global__ void cvt_codebook(const float* __restrict__ cb, u8* __restrict__ cbq,
                             float* __restrict__ cnorm) {
  int k = blockIdx.x;          // 0..4095
  int t = threadIdx.x;         // 0..255, handles elems 2t, 2t+1
  float c0 = cb[(size_t)k * DIM + 2 * t];
  float c1 = cb[(size_t)k * DIM + 2 * t + 1];
  int pk = __builtin_amdgcn_cvt_pk_fp8_f32(c0 * 4096.f, c1 * 4096.f, 0, false);
  int h = (k >> 1) & 7;
  size_t dst = (size_t)k * 512 + (t >> 5) * 64
             + (size_t)(((t >> 2) & 7) ^ h) * 8 + (t & 3) * 2;
  *reinterpret_cast<u16*>(cbq + dst) = (u16)(pk & 0xffff);
  float s = c0 * c0 + c1 * c1;
#pragma unroll
  for (int m = 1; m < 64; m <<= 1) s += __shfl_xor(s, m, 64);
  __shared__ float w4[4];
  if ((t & 63) == 0) w4[t >> 6] = s;
  __syncthreads();
  if (t == 0) cnorm[k] = w4[0] + w4[1] + w4[2] + w4[3];
}

// ---------------- argmin GEMM (fp8): scores = cnorm[k] - 2 x.c -------------
// R6 structure (verified 148us): 128x256 tile, BK=64, 8 waves (2M x 4N),
// fp8 e4m3 mfma 16x16x32, counted-vmcnt 2-tile-deep. NEW: swizzle baked into
// global layout (cvt_x/cvt_codebook) -> linear stage + 3-bit 8B-granular
// XOR on read = bank-conflict-free ds_read_b64 (each bank exactly 4x = min).
__global__ __launch_bounds__(512, 4)
void argmin_fp8(const u8* __restrict__ Xq, const u8* __restrict__ Cq,
                const float* __restrict__ cnorm,
                float* __restrict__ pval, int* __restrict__ pidx) {
  __shared__ u8 As[2][128 * 64];   // 8 KiB each
  __shared__ u8 Bs[2][256 * 64];   // 16 KiB each  (48 KiB total)

  const int tid  = threadIdx.x;
  const int lane = tid & 63;
  const int wid  = tid >> 6;          // 0..7
  const int wr   = wid >> 2;          // 0..1 (M half: 64 rows)
  const int wc   = wid & 3;           // 0..3 (N quarter: 64 cols)
  const int bm   = blockIdx.x;        // 0..255 token tiles (128 each)
  const int bn   = blockIdx.y;        // 0..15  code tiles (256 each)
  const int l15  = lane & 15, l4 = lane >> 4;

  const u8* Xg = Xq + (size_t)(bm * 128) * DIM;
  const u8* Cg = Cq + (size_t)(bn * 256) * DIM;

  // stage one K-tile: A 128x64B (1 pass) + B 256x64B (2 passes) = 3 gloads.
  // Pure linear copy — the permutation lives in the global data layout.
  auto stage = [&](int buf, int kt) {
    int kk = kt * 64;
    {
      int row = wid * 16 + (lane >> 2);            // 0..127
      gload_lds16(Xg + (size_t)row * DIM + kk + (lane & 3) * 16,
                  (void*)(As[buf] + wid * 1024));
    }
#pragma unroll
    for (int p = 0; p < 2; p++) {
      int row = p * 128 + wid * 16 + (lane >> 2);  // 0..255
      gload_lds16(Cg + (size_t)row * DIM + kk + (lane & 3) * 16,
                  (void*)(Bs[buf] + p * 8192 + wid * 1024));
    }
  };

  // swizzled 8B fragment read: logical slot s8 -> phys = s8 ^ ((row>>1)&7)
  auto rd8 = [&](const u8* base, int row, int s8) -> long long {
    int addr = row * 64 + ((s8 ^ ((row >> 1) & 7)) << 3);
    return *reinterpret_cast<const long long*>(base + addr);
  };

  f32x4 acc[4][4];
#pragma unroll
  for (int i = 0; i < 4; i++)
#pragma unroll
    for (int j = 0; j < 4; j++)
#pragma unroll
      for (int r = 0; r < 4; r++) acc[i][j][r] = 0.f;

  stage(0, 0);
  stage(1, 1);
  asm volatile("s_waitcnt vmcnt(3)" ::: "memory");   // tile0's 3 landed
  __builtin_amdgcn_s_barrier();
  asm volatile("" ::: "memory");

  for (int t = 0; t < 8; ++t) {
    const u8* A  = As[t & 1];
    const u8* Bt = Bs[t & 1];
    long long bfr[4][2];
#pragma unroll
    for (int ni = 0; ni < 4; ni++)
#pragma unroll
      for (int ks = 0; ks < 2; ks++)
        bfr[ni][ks] = rd8(Bt, wc * 64 + ni * 16 + l15, ks * 4 + l4);
#pragma unroll
    for (int mi = 0; mi < 4; mi++) {
      long long af0 = rd8(A, wr * 64 + mi * 16 + l15, l4);
      long long af1 = rd8(A, wr * 64 + mi * 16 + l15, 4 + l4);
      __builtin_amdgcn_s_setprio(1);
#pragma unroll
      for (int ni = 0; ni < 4; ni++) {
        acc[mi][ni] = __builtin_amdgcn_mfma_f32_16x16x32_fp8_fp8(
            af0, bfr[ni][0], acc[mi][ni], 0, 0, 0);
        acc[mi][ni] = __builtin_amdgcn_mfma_f32_16x16x32_fp8_fp8(
            af1, bfr[ni][1], acc[mi][ni], 0, 0, 0);
      }
      __builtin_amdgcn_s_setprio(0);
    }

    asm volatile("" ::: "memory");
    __builtin_amdgcn_s_barrier();          // all waves done reading buf[t&1]
    asm volatile("" ::: "memory");
    if (t + 2 < 8) {
      stage(t & 1, t + 2);                 // refill freed buffer (3 loads)
      asm volatile("s_waitcnt vmcnt(3)" ::: "memory");   // tile t+1 landed
      __builtin_amdgcn_s_barrier();
      asm volatile("" ::: "memory");
    } else if (t < 7) {
      asm volatile("s_waitcnt vmcnt(0)" ::: "memory");
      __builtin_amdgcn_s_barrier();
      asm volatile("" ::: "memory");
    }
  }

  // -------- epilogue: per-token argmin over this block's 256 codes ---------
  // scores = cnorm - (2/4096) * acc   (codebook was pre-scaled by 4096)
  const float SC = 4.8828125e-4f;   // 2^-11
  float* rv = (float*)As;   // [4][128]
  int*   ri = (int*)Bs;
  __syncthreads();

#pragma unroll
  for (int mi = 0; mi < 4; mi++) {
#pragma unroll
    for (int r = 0; r < 4; r++) {
      float best = 1e30f;
      int bi = 0;
#pragma unroll
      for (int ni = 0; ni < 4; ni++) {
        int code = bn * 256 + wc * 64 + ni * 16 + l15;
        float v = cnorm[code] - SC * acc[mi][ni][r];
        if (v < best) { best = v; bi = code; }
      }
#pragma unroll
      for (int m = 1; m < 16; m <<= 1) {
        float ov = __shfl_xor(best, m, 64);
        int   oi = __shfl_xor(bi, m, 64);
        if (ov < best) { best = ov; bi = oi; }
      }
      if (l15 == 0) {
        int tok = wr * 64 + mi * 16 + l4 * 4 + r;   // 0..127
        rv[wc * 128 + tok] = best;
        ri[wc * 128 + tok] = bi;
      }
    }
  }
  __syncthreads();
  if (tid < 128) {
    float bv = rv[tid];
    int   bb = ri[tid];
#pragma unroll
    for (int c = 1; c < 4; c++) {
      float v = rv[c * 128 + tid];
      if (v < bv) { bv = v; bb = ri[c * 128 + tid]; }
    }
    size_t g = (size_t)bn * NTOK + bm * 128 + tid;
    pval[g] = bv;
    pidx[g] = bb;
  }
}

__global__ void argmin_reduce(const float* __restrict__ pval, const int* __restrict__ pidx,
                              int* __restrict__ idx) {
  int t = blockIdx.x * 256 + threadIdx.x;   // 0..32767
  float best = 1e30f;
  int bi = 0;
  for (int c = 0; c < 16; c++) {
    float v = pval[(size_t)c * NTOK + t];
    if (v < best) { best = v; bi = pidx[(size_t)c * NTOK + t]; }
  }
  idx[t] = bi;
}

// ---------- gate GEMM (X @ W^T) + fused epilogue + deterministic loss -------
__global__ __launch_bounds__(256)
void gate_out(const u16* __restrict__ Xb, const u16* __restrict__ Wb,
              const float* __restrict__ X, const float* __restrict__ Cf,
              const float* __restrict__ gb, const int* __restrict__ idx,
              float* __restrict__ out, float* __restrict__ blockSum) {
  __shared__ u16 As[2][128 * 64];
  __shared__ u16 Bs[2][128 * 64];
  __shared__ float bsum[4];

  const int tid  = threadIdx.x;
  const int lane = tid & 63;
  const int wid  = tid >> 6;
  const int wr   = wid >> 1, wc = wid & 1;
  const int bm   = blockIdx.x;        // 0..255
  const int bn   = blockIdx.y;        // 0..3
  const int l15  = lane & 15, l4 = lane >> 4;
  const int srow = lane >> 3;
  const int scol = (((lane & 7) ^ (lane >> 3)) & 7) * 8;

  const u16* Xrow = Xb + (size_t)(bm * 128) * DIM;
  const u16* Wrow = Wb + (size_t)(bn * 128) * DIM;

  auto stage = [&](int buf, int kk) {
#pragma unroll
    for (int i = 0; i < 4; i++) {
      int rA = (wid * 4 + i) * 8 + srow;
      gload_lds16(Xrow + (size_t)rA * DIM + kk + scol,
                  (void*)(As[buf] + (wid * 4 + i) * 512));
      gload_lds16(Wrow + (size_t)rA * DIM + kk + scol,
                  (void*)(Bs[buf] + (wid * 4 + i) * 512));
    }
  };

  f32x4 acc[4][4];
#pragma unroll
  for (int i = 0; i < 4; i++)
#pragma unroll
    for (int j = 0; j < 4; j++)
#pragma unroll
      for (int r = 0; r < 4; r++) acc[i][j][r] = 0.f;

  stage(0, 0);
  __syncthreads();
  int cur = 0;
  for (int t = 0; t < 8; ++t) {
    if (t < 7) stage(cur ^ 1, (t + 1) * 64);
#pragma unroll
    for (int ks = 0; ks < 2; ks++) {
      bf16x8 af[4], bfr[4];
#pragma unroll
      for (int mi = 0; mi < 4; mi++) {
        int row = wr * 64 + mi * 16 + l15;
        int col = (ks * 32 + l4 * 8) ^ ((row & 7) << 3);
        af[mi] = *reinterpret_cast<const bf16x8*>(As[cur] + row * 64 + col);
      }
#pragma unroll
      for (int ni = 0; ni < 4; ni++) {
        int row = wc * 64 + ni * 16 + l15;
        int col = (ks * 32 + l4 * 8) ^ ((row & 7) << 3);
        bfr[ni] = *reinterpret_cast<const bf16x8*>(Bs[cur] + row * 64 + col);
      }
#pragma unroll
      for (int mi = 0; mi < 4; mi++)
#pragma unroll
        for (int ni = 0; ni < 4; ni++)
          acc[mi][ni] = __builtin_amdgcn_mfma_f32_16x16x32_bf16(
              af[mi], bfr[ni], acc[mi][ni], 0, 0, 0);
    }
    __syncthreads();
    cur ^= 1;
  }

  // epilogue: gate = sigmoid(acc + b), out = x + c[idx]*gate, loss partial
  float lsum = 0.f;
#pragma unroll
  for (int mi = 0; mi < 4; mi++) {
#pragma unroll
    for (int r = 0; r < 4; r++) {
      int token = bm * 128 + wr * 64 + mi * 16 + l4 * 4 + r;
      int code = idx[token];
#pragma unroll
      for (int ni = 0; ni < 4; ni++) {
        int col = bn * 128 + wc * 64 + ni * 16 + l15;
        float logit = acc[mi][ni][r] + gb[col];
        float g = 1.0f / (1.0f + __expf(-logit));
        float q = Cf[(size_t)code * DIM + col];
        float xx = X[(size_t)token * DIM + col];
        out[(size_t)token * DIM + col] = xx + q * g;
        float d = q - xx;
        lsum += d * d;
      }
    }
  }
#pragma unroll
  for (int m = 1; m < 64; m <<= 1) lsum += __shfl_xor(lsum, m, 64);
  if (lane == 0) bsum[wid] = lsum;
  __syncthreads();
  if (tid == 0)
    blockSum[blockIdx.y * gridDim.x + blockIdx.x] = bsum[0] + bsum[1] + bsum[2] + bsum[3];
}

__global__ void finalize(const float* __restrict__ blockSum, float* __restrict__ out_loss) {
  int t = threadIdx.x;  // 256 threads, 1024 partials
  float s = 0.f;
#pragma unroll
  for (int i = 0; i < 4; i++) s += blockSum[t * 4 + i];
#pragma unroll
  for (int m = 1; m < 64; m <<= 1) s += __shfl_xor(s, m, 64);
  __shared__ float w4[4];
  if ((t & 63) == 0) w4[t >> 6] = s;
  __syncthreads();
  if (t == 0) {
    float tot = w4[0] + w4[1] + w4[2] + w4[3];
    out_loss[0] = 1.25f * tot / 16777216.0f;   // N*D = 32768*512
  }
}

extern "C" void kernel_launch(void* const* d_in, const int* in_sizes, int n_in,
                              void* d_out, int out_size, void* d_ws, size_t ws_size,
                              hipStream_t stream) {
  const float* X  = (const float*)d_in[0];   // [32768, 512]
  const float* CB = (const float*)d_in[1];   // [4096, 512]
  const float* GW = (const float*)d_in[2];   // [512, 512]
  const float* GB = (const float*)d_in[3];   // [512]
  float* out = (float*)d_out;                // [32768*512] output + [1] loss

  char* w = (char*)d_ws;
  size_t off = 0;
  auto alloc = [&](size_t bytes) -> void* {
    void* p = w + off;
    off = (off + bytes + 255) & ~(size_t)255;
    return p;
  };
  u16*   Xb    = (u16*)alloc((size_t)NTOK * DIM * 2);   // 33.5 MB (gate)
  u8*    Xq    = (u8*) alloc((size_t)NTOK * DIM);       // 16.8 MB (argmin, swz)
  u8*    Cq    = (u8*) alloc((size_t)KC * DIM);         // 2.1 MB (argmin, swz)
  u16*   Wb    = (u16*)alloc((size_t)DIM * DIM * 2);    // 0.5 MB
  float* cnorm = (float*)alloc((size_t)KC * 4);
  float* pval  = (float*)alloc((size_t)16 * NTOK * 4);  // 2.1 MB
  int*   pidx  = (int*)alloc((size_t)16 * NTOK * 4);    // 2.1 MB
  int*   idx   = (int*)alloc((size_t)NTOK * 4);
  float* bsums = (float*)alloc((size_t)1024 * 4);

  cvt_x<<<8192, 256, 0, stream>>>(X, Xb, Xq, NTOK * DIM / 8);
  cvt8<<<128, 256, 0, stream>>>(GW, Wb, DIM * DIM / 8);
  cvt_codebook<<<KC, 256, 0, stream>>>(CB, Cq, cnorm);
  argmin_fp8<<<dim3(256, 16), 512, 0, stream>>>(Xq, Cq, cnorm, pval, pidx);
  argmin_reduce<<<128, 256, 0, stream>>>(pval, pidx, idx);
  gate_out<<<dim3(256, 4), 256, 0, stream>>>(Xb, Wb, X, CB, GB, idx, out, bsums);
  finalize<<<1, 256, 0, stream>>>(bsums, out + (size_t)NTOK * DIM);
}

// Round 12
// 198.904 us; speedup vs baseline: 2.8831x; 1.1305x over previous
//
#include <hip/hip_runtime.h>
#include <hip/hip_bf16.h>

typedef unsigned short u16;
typedef unsigned char u8;
typedef float f32x4 __attribute__((ext_vector_type(4)));

#define NTOK 32768   // B*S = 8*4096
#define DIM  512
#define KC   4096

__device__ __forceinline__ void gload_lds16(const void* g, void* l) {
  __builtin_amdgcn_global_load_lds(
      (__attribute__((address_space(1))) void*)g,
      (__attribute__((address_space(3))) void*)l,
      16, 0, 0);
}

// -------- prep: X fp32 -> fp8 e4m3, swizzled global layout -----------------
// Within each 64B K-chunk of each row, 8B block s8 lives at phys
// s8 ^ ((row>>1)&7)  -> bank-conflict-free ds_read_b64 fragments (R11: 0 conf).
__global__ void cvt_x(const float* __restrict__ in, u8* __restrict__ q, int n8) {
  int i = blockIdx.x * blockDim.x + threadIdx.x;
  if (i >= n8) return;
  const float4* p = reinterpret_cast<const float4*>(in) + 2 * (size_t)i;
  float4 a = p[0], b = p[1];
  int u0 = __builtin_amdgcn_cvt_pk_fp8_f32(a.x, a.y, 0, false);
  u0     = __builtin_amdgcn_cvt_pk_fp8_f32(a.z, a.w, u0, true);
  int u1 = __builtin_amdgcn_cvt_pk_fp8_f32(b.x, b.y, 0, false);
  u1     = __builtin_amdgcn_cvt_pk_fp8_f32(b.z, b.w, u1, true);
  uint2 w2; w2.x = (unsigned)u0; w2.y = (unsigned)u1;
  int row   = i >> 6;            // i indexes 8B blocks; 64 per row
  int s8l   = i & 63;
  int chunk = s8l >> 3;
  int s8in  = s8l & 7;
  int h     = (row >> 1) & 7;
  size_t dst = (size_t)row * 512 + chunk * 64 + (size_t)(s8in ^ h) * 8;
  *reinterpret_cast<uint2*>(q + dst) = w2;
}

// gate W -> fp8 scaled x16 (avoids e4m3 subnormal floor), swizzled layout
__global__ void cvt_w(const float* __restrict__ w, u8* __restrict__ wq) {
  int k = blockIdx.x;          // 0..511 rows
  int t = threadIdx.x;         // 0..255, elems 2t, 2t+1
  float c0 = w[(size_t)k * DIM + 2 * t] * 16.f;
  float c1 = w[(size_t)k * DIM + 2 * t + 1] * 16.f;
  int pk = __builtin_amdgcn_cvt_pk_fp8_f32(c0, c1, 0, false);
  int h = (k >> 1) & 7;
  size_t dst = (size_t)k * 512 + (t >> 5) * 64
             + (size_t)(((t >> 2) & 7) ^ h) * 8 + (t & 3) * 2;
  *reinterpret_cast<u16*>(wq + dst) = (u16)(pk & 0xffff);
}

// codebook -> fp8 scaled by 4096 (values in ±1), swizzled layout, exact norms
__global__ void cvt_codebook(const float* __restrict__ cb, u8* __restrict__ cbq,
                             float* __restrict__ cnorm) {
  int k = blockIdx.x;          // 0..4095
  int t = threadIdx.x;         // 0..255, elems 2t, 2t+1
  float c0 = cb[(size_t)k * DIM + 2 * t];
  float c1 = cb[(size_t)k * DIM + 2 * t + 1];
  int pk = __builtin_amdgcn_cvt_pk_fp8_f32(c0 * 4096.f, c1 * 4096.f, 0, false);
  int h = (k >> 1) & 7;
  size_t dst = (size_t)k * 512 + (t >> 5) * 64
             + (size_t)(((t >> 2) & 7) ^ h) * 8 + (t & 3) * 2;
  *reinterpret_cast<u16*>(cbq + dst) = (u16)(pk & 0xffff);
  float s = c0 * c0 + c1 * c1;
#pragma unroll
  for (int m = 1; m < 64; m <<= 1) s += __shfl_xor(s, m, 64);
  __shared__ float w4[4];
  if ((t & 63) == 0) w4[t >> 6] = s;
  __syncthreads();
  if (t == 0) cnorm[k] = w4[0] + w4[1] + w4[2] + w4[3];
}

// ---------------- argmin GEMM (fp8): scores = cnorm[k] - 2 x.c -------------
// R11-verified: 128x256 tile, BK=64, 8 waves (2M x 4N), fp8 e4m3 16x16x32,
// counted-vmcnt 2-tile-deep, swizzle in global layout, 0 bank conflicts.
__global__ __launch_bounds__(512, 4)
void argmin_fp8(const u8* __restrict__ Xq, const u8* __restrict__ Cq,
                const float* __restrict__ cnorm,
                float* __restrict__ pval, int* __restrict__ pidx) {
  __shared__ u8 As[2][128 * 64];   // 8 KiB each
  __shared__ u8 Bs[2][256 * 64];   // 16 KiB each  (48 KiB total)

  const int tid  = threadIdx.x;
  const int lane = tid & 63;
  const int wid  = tid >> 6;          // 0..7
  const int wr   = wid >> 2;          // 0..1 (M half: 64 rows)
  const int wc   = wid & 3;           // 0..3 (N quarter: 64 cols)
  const int bm   = blockIdx.x;        // 0..255 token tiles (128 each)
  const int bn   = blockIdx.y;        // 0..15  code tiles (256 each)
  const int l15  = lane & 15, l4 = lane >> 4;

  const u8* Xg = Xq + (size_t)(bm * 128) * DIM;
  const u8* Cg = Cq + (size_t)(bn * 256) * DIM;

  auto stage = [&](int buf, int kt) {
    int kk = kt * 64;
    {
      int row = wid * 16 + (lane >> 2);            // 0..127
      gload_lds16(Xg + (size_t)row * DIM + kk + (lane & 3) * 16,
                  (void*)(As[buf] + wid * 1024));
    }
#pragma unroll
    for (int p = 0; p < 2; p++) {
      int row = p * 128 + wid * 16 + (lane >> 2);  // 0..255
      gload_lds16(Cg + (size_t)row * DIM + kk + (lane & 3) * 16,
                  (void*)(Bs[buf] + p * 8192 + wid * 1024));
    }
  };

  auto rd8 = [&](const u8* base, int row, int s8) -> long long {
    int addr = row * 64 + ((s8 ^ ((row >> 1) & 7)) << 3);
    return *reinterpret_cast<const long long*>(base + addr);
  };

  f32x4 acc[4][4];
#pragma unroll
  for (int i = 0; i < 4; i++)
#pragma unroll
    for (int j = 0; j < 4; j++)
#pragma unroll
      for (int r = 0; r < 4; r++) acc[i][j][r] = 0.f;

  stage(0, 0);
  stage(1, 1);
  asm volatile("s_waitcnt vmcnt(3)" ::: "memory");
  __builtin_amdgcn_s_barrier();
  asm volatile("" ::: "memory");

  for (int t = 0; t < 8; ++t) {
    const u8* A  = As[t & 1];
    const u8* Bt = Bs[t & 1];
    long long bfr[4][2];
#pragma unroll
    for (int ni = 0; ni < 4; ni++)
#pragma unroll
      for (int ks = 0; ks < 2; ks++)
        bfr[ni][ks] = rd8(Bt, wc * 64 + ni * 16 + l15, ks * 4 + l4);
#pragma unroll
    for (int mi = 0; mi < 4; mi++) {
      long long af0 = rd8(A, wr * 64 + mi * 16 + l15, l4);
      long long af1 = rd8(A, wr * 64 + mi * 16 + l15, 4 + l4);
      __builtin_amdgcn_s_setprio(1);
#pragma unroll
      for (int ni = 0; ni < 4; ni++) {
        acc[mi][ni] = __builtin_amdgcn_mfma_f32_16x16x32_fp8_fp8(
            af0, bfr[ni][0], acc[mi][ni], 0, 0, 0);
        acc[mi][ni] = __builtin_amdgcn_mfma_f32_16x16x32_fp8_fp8(
            af1, bfr[ni][1], acc[mi][ni], 0, 0, 0);
      }
      __builtin_amdgcn_s_setprio(0);
    }

    asm volatile("" ::: "memory");
    __builtin_amdgcn_s_barrier();
    asm volatile("" ::: "memory");
    if (t + 2 < 8) {
      stage(t & 1, t + 2);
      asm volatile("s_waitcnt vmcnt(3)" ::: "memory");
      __builtin_amdgcn_s_barrier();
      asm volatile("" ::: "memory");
    } else if (t < 7) {
      asm volatile("s_waitcnt vmcnt(0)" ::: "memory");
      __builtin_amdgcn_s_barrier();
      asm volatile("" ::: "memory");
    }
  }

  // epilogue: per-token argmin over this block's 256 codes
  const float SC = 4.8828125e-4f;   // 2/4096
  float* rv = (float*)As;
  int*   ri = (int*)Bs;
  __syncthreads();

#pragma unroll
  for (int mi = 0; mi < 4; mi++) {
#pragma unroll
    for (int r = 0; r < 4; r++) {
      float best = 1e30f;
      int bi = 0;
#pragma unroll
      for (int ni = 0; ni < 4; ni++) {
        int code = bn * 256 + wc * 64 + ni * 16 + l15;
        float v = cnorm[code] - SC * acc[mi][ni][r];
        if (v < best) { best = v; bi = code; }
      }
#pragma unroll
      for (int m = 1; m < 16; m <<= 1) {
        float ov = __shfl_xor(best, m, 64);
        int   oi = __shfl_xor(bi, m, 64);
        if (ov < best) { best = ov; bi = oi; }
      }
      if (l15 == 0) {
        int tok = wr * 64 + mi * 16 + l4 * 4 + r;
        rv[wc * 128 + tok] = best;
        ri[wc * 128 + tok] = bi;
      }
    }
  }
  __syncthreads();
  if (tid < 128) {
    float bv = rv[tid];
    int   bb = ri[tid];
#pragma unroll
    for (int c = 1; c < 4; c++) {
      float v = rv[c * 128 + tid];
      if (v < bv) { bv = v; bb = ri[c * 128 + tid]; }
    }
    size_t g = (size_t)bn * NTOK + bm * 128 + tid;
    pval[g] = bv;
    pidx[g] = bb;
  }
}

__global__ void argmin_reduce(const float* __restrict__ pval, const int* __restrict__ pidx,
                              int* __restrict__ idx) {
  int t = blockIdx.x * 256 + threadIdx.x;   // 0..32767
  float best = 1e30f;
  int bi = 0;
  for (int c = 0; c < 16; c++) {
    float v = pval[(size_t)c * NTOK + t];
    if (v < best) { best = v; bi = pidx[(size_t)c * NTOK + t]; }
  }
  idx[t] = bi;
}

// ------- gate GEMM (fp8, argmin structure) + fused epilogue + loss ---------
// logit = 2^-4 * (fp8(x) . fp8(16 w)) + b  — gate precision is uncritical:
// |q| <= 2.4e-4 so out-error = q*dGate <= ~1e-4 even with ~2 logit-std error.
// Output passthrough x and loss use exact fp32 X and fp32 codebook gather.
__global__ __launch_bounds__(512, 4)
void gate_fp8(const u8* __restrict__ Xq, const u8* __restrict__ Wq,
              const float* __restrict__ X, const float* __restrict__ Cf,
              const float* __restrict__ gb, const int* __restrict__ idx,
              float* __restrict__ out, float* __restrict__ blockSum) {
  __shared__ u8 As[2][128 * 64];
  __shared__ u8 Bs[2][256 * 64];
  __shared__ float bsum[8];

  const int tid  = threadIdx.x;
  const int lane = tid & 63;
  const int wid  = tid >> 6;          // 0..7
  const int wr   = wid >> 2;          // 0..1
  const int wc   = wid & 3;           // 0..3
  const int bm   = blockIdx.x;        // 0..255 token tiles
  const int bn   = blockIdx.y;        // 0..1   col tiles (256 each)
  const int l15  = lane & 15, l4 = lane >> 4;

  const u8* Xg = Xq + (size_t)(bm * 128) * DIM;
  const u8* Wg = Wq + (size_t)(bn * 256) * DIM;

  auto stage = [&](int buf, int kt) {
    int kk = kt * 64;
    {
      int row = wid * 16 + (lane >> 2);
      gload_lds16(Xg + (size_t)row * DIM + kk + (lane & 3) * 16,
                  (void*)(As[buf] + wid * 1024));
    }
#pragma unroll
    for (int p = 0; p < 2; p++) {
      int row = p * 128 + wid * 16 + (lane >> 2);
      gload_lds16(Wg + (size_t)row * DIM + kk + (lane & 3) * 16,
                  (void*)(Bs[buf] + p * 8192 + wid * 1024));
    }
  };

  auto rd8 = [&](const u8* base, int row, int s8) -> long long {
    int addr = row * 64 + ((s8 ^ ((row >> 1) & 7)) << 3);
    return *reinterpret_cast<const long long*>(base + addr);
  };

  f32x4 acc[4][4];
#pragma unroll
  for (int i = 0; i < 4; i++)
#pragma unroll
    for (int j = 0; j < 4; j++)
#pragma unroll
      for (int r = 0; r < 4; r++) acc[i][j][r] = 0.f;

  stage(0, 0);
  stage(1, 1);
  asm volatile("s_waitcnt vmcnt(3)" ::: "memory");
  __builtin_amdgcn_s_barrier();
  asm volatile("" ::: "memory");

  for (int t = 0; t < 8; ++t) {
    const u8* A  = As[t & 1];
    const u8* Bt = Bs[t & 1];
    long long bfr[4][2];
#pragma unroll
    for (int ni = 0; ni < 4; ni++)
#pragma unroll
      for (int ks = 0; ks < 2; ks++)
        bfr[ni][ks] = rd8(Bt, wc * 64 + ni * 16 + l15, ks * 4 + l4);
#pragma unroll
    for (int mi = 0; mi < 4; mi++) {
      long long af0 = rd8(A, wr * 64 + mi * 16 + l15, l4);
      long long af1 = rd8(A, wr * 64 + mi * 16 + l15, 4 + l4);
      __builtin_amdgcn_s_setprio(1);
#pragma unroll
      for (int ni = 0; ni < 4; ni++) {
        acc[mi][ni] = __builtin_amdgcn_mfma_f32_16x16x32_fp8_fp8(
            af0, bfr[ni][0], acc[mi][ni], 0, 0, 0);
        acc[mi][ni] = __builtin_amdgcn_mfma_f32_16x16x32_fp8_fp8(
            af1, bfr[ni][1], acc[mi][ni], 0, 0, 0);
      }
      __builtin_amdgcn_s_setprio(0);
    }

    asm volatile("" ::: "memory");
    __builtin_amdgcn_s_barrier();
    asm volatile("" ::: "memory");
    if (t + 2 < 8) {
      stage(t & 1, t + 2);
      asm volatile("s_waitcnt vmcnt(3)" ::: "memory");
      __builtin_amdgcn_s_barrier();
      asm volatile("" ::: "memory");
    } else if (t < 7) {
      asm volatile("s_waitcnt vmcnt(0)" ::: "memory");
      __builtin_amdgcn_s_barrier();
      asm volatile("" ::: "memory");
    }
  }

  // epilogue: gate = sigmoid(2^-4*acc + b), out = x + c[idx]*gate, loss
  const float SCW = 0.0625f;   // 2^-4 (W was scaled x16)
  float lsum = 0.f;
#pragma unroll
  for (int mi = 0; mi < 4; mi++) {
#pragma unroll
    for (int r = 0; r < 4; r++) {
      int token = bm * 128 + wr * 64 + mi * 16 + l4 * 4 + r;
      int code = idx[token];
#pragma unroll
      for (int ni = 0; ni < 4; ni++) {
        int col = bn * 256 + wc * 64 + ni * 16 + l15;
        float logit = SCW * acc[mi][ni][r] + gb[col];
        float g = 1.0f / (1.0f + __expf(-logit));
        float q = Cf[(size_t)code * DIM + col];
        float xx = X[(size_t)token * DIM + col];
        out[(size_t)token * DIM + col] = xx + q * g;
        float d = q - xx;
        lsum += d * d;
      }
    }
  }
#pragma unroll
  for (int m = 1; m < 64; m <<= 1) lsum += __shfl_xor(lsum, m, 64);
  if (lane == 0) bsum[wid] = lsum;
  __syncthreads();
  if (tid == 0) {
    float s = 0.f;
#pragma unroll
    for (int i = 0; i < 8; i++) s += bsum[i];
    blockSum[blockIdx.y * gridDim.x + blockIdx.x] = s;
  }
}

__global__ void finalize(const float* __restrict__ blockSum, float* __restrict__ out_loss) {
  int t = threadIdx.x;  // 256 threads, 512 partials
  float s = blockSum[t * 2] + blockSum[t * 2 + 1];
#pragma unroll
  for (int m = 1; m < 64; m <<= 1) s += __shfl_xor(s, m, 64);
  __shared__ float w4[4];
  if ((t & 63) == 0) w4[t >> 6] = s;
  __syncthreads();
  if (t == 0) {
    float tot = w4[0] + w4[1] + w4[2] + w4[3];
    out_loss[0] = 1.25f * tot / 16777216.0f;   // N*D = 32768*512
  }
}

extern "C" void kernel_launch(void* const* d_in, const int* in_sizes, int n_in,
                              void* d_out, int out_size, void* d_ws, size_t ws_size,
                              hipStream_t stream) {
  const float* X  = (const float*)d_in[0];   // [32768, 512]
  const float* CB = (const float*)d_in[1];   // [4096, 512]
  const float* GW = (const float*)d_in[2];   // [512, 512]
  const float* GB = (const float*)d_in[3];   // [512]
  float* out = (float*)d_out;                // [32768*512] output + [1] loss

  char* w = (char*)d_ws;
  size_t off = 0;
  auto alloc = [&](size_t bytes) -> void* {
    void* p = w + off;
    off = (off + bytes + 255) & ~(size_t)255;
    return p;
  };
  u8*    Xq    = (u8*) alloc((size_t)NTOK * DIM);       // 16.8 MB (swizzled fp8)
  u8*    Cq    = (u8*) alloc((size_t)KC * DIM);         // 2.1 MB (swizzled, x4096)
  u8*    Wq    = (u8*) alloc((size_t)DIM * DIM);        // 0.25 MB (swizzled, x16)
  float* cnorm = (float*)alloc((size_t)KC * 4);
  float* pval  = (float*)alloc((size_t)16 * NTOK * 4);  // 2.1 MB
  int*   pidx  = (int*)alloc((size_t)16 * NTOK * 4);    // 2.1 MB
  int*   idx   = (int*)alloc((size_t)NTOK * 4);
  float* bsums = (float*)alloc((size_t)512 * 4);

  cvt_x<<<8192, 256, 0, stream>>>(X, Xq, NTOK * DIM / 8);
  cvt_w<<<DIM, 256, 0, stream>>>(GW, Wq);
  cvt_codebook<<<KC, 256, 0, stream>>>(CB, Cq, cnorm);
  argmin_fp8<<<dim3(256, 16), 512, 0, stream>>>(Xq, Cq, cnorm, pval, pidx);
  argmin_reduce<<<128, 256, 0, stream>>>(pval, pidx, idx);
  gate_fp8<<<dim3(256, 2), 512, 0, stream>>>(Xq, Wq, X, CB, GB, idx, out, bsums);
  finalize<<<1, 256, 0, stream>>>(bsums, out + (size_t)NTOK * DIM);
}

// Round 13
// 189.011 us; speedup vs baseline: 3.0340x; 1.0523x over previous
//
#include <hip/hip_runtime.h>
#include <hip/hip_bf16.h>

typedef unsigned short u16;
typedef unsigned char u8;
typedef float f32x4 __attribute__((ext_vector_type(4)));
typedef int i32x4 __attribute__((ext_vector_type(4)));

#define NTOK 32768   // B*S = 8*4096
#define DIM  512
#define KC   4096

__device__ __forceinline__ void gload_lds16(const void* g, void* l) {
  __builtin_amdgcn_global_load_lds(
      (__attribute__((address_space(1))) void*)g,
      (__attribute__((address_space(3))) void*)l,
      16, 0, 0);
}

__device__ __forceinline__ unsigned pk4(float a, float b, float c, float d, float inv) {
  int b0 = __float2int_rn(a * inv), b1 = __float2int_rn(b * inv);
  int b2 = __float2int_rn(c * inv), b3 = __float2int_rn(d * inv);
  return (unsigned)(b0 & 255) | ((unsigned)(b1 & 255) << 8) |
         ((unsigned)(b2 & 255) << 16) | ((unsigned)(b3 & 255) << 24);
}

// ---- prep: X fp32 -> i8 per-token symmetric quant (linear layout) ---------
// one wave per row; xs[row] = maxabs/127
__global__ void cvt_x_i8(const float* __restrict__ in, u8* __restrict__ q,
                         float* __restrict__ xs) {
  int row  = blockIdx.x * 4 + (threadIdx.x >> 6);
  int lane = threadIdx.x & 63;
  const float* src = in + (size_t)row * DIM + lane * 8;
  float4 a = *reinterpret_cast<const float4*>(src);
  float4 b = *reinterpret_cast<const float4*>(src + 4);
  float m = fmaxf(fmaxf(fmaxf(fabsf(a.x), fabsf(a.y)), fmaxf(fabsf(a.z), fabsf(a.w))),
                  fmaxf(fmaxf(fabsf(b.x), fabsf(b.y)), fmaxf(fabsf(b.z), fabsf(b.w))));
#pragma unroll
  for (int s = 1; s < 64; s <<= 1) m = fmaxf(m, __shfl_xor(m, s, 64));
  float inv = 127.0f / fmaxf(m, 1e-20f);
  uint2 w2;
  w2.x = pk4(a.x, a.y, a.z, a.w, inv);
  w2.y = pk4(b.x, b.y, b.z, b.w, inv);
  *reinterpret_cast<uint2*>(q + (size_t)row * DIM + lane * 8) = w2;
  if (lane == 0) xs[row] = m * (1.0f / 127.0f);
}

// codebook -> i8 per-code quant + exact fp32 norm; cs2[k] = 2*maxabs/127
__global__ void cvt_cb_i8(const float* __restrict__ cb, u8* __restrict__ cq,
                          float* __restrict__ cnorm, float* __restrict__ cs2) {
  int row  = blockIdx.x * 4 + (threadIdx.x >> 6);
  int lane = threadIdx.x & 63;
  const float* src = cb + (size_t)row * DIM + lane * 8;
  float4 a = *reinterpret_cast<const float4*>(src);
  float4 b = *reinterpret_cast<const float4*>(src + 4);
  float m = fmaxf(fmaxf(fmaxf(fabsf(a.x), fabsf(a.y)), fmaxf(fabsf(a.z), fabsf(a.w))),
                  fmaxf(fmaxf(fabsf(b.x), fabsf(b.y)), fmaxf(fabsf(b.z), fabsf(b.w))));
  float s = a.x*a.x + a.y*a.y + a.z*a.z + a.w*a.w
          + b.x*b.x + b.y*b.y + b.z*b.z + b.w*b.w;
#pragma unroll
  for (int sh = 1; sh < 64; sh <<= 1) {
    m = fmaxf(m, __shfl_xor(m, sh, 64));
    s += __shfl_xor(s, sh, 64);
  }
  float inv = 127.0f / fmaxf(m, 1e-20f);
  uint2 w2;
  w2.x = pk4(a.x, a.y, a.z, a.w, inv);
  w2.y = pk4(b.x, b.y, b.z, b.w, inv);
  *reinterpret_cast<uint2*>(cq + (size_t)row * DIM + lane * 8) = w2;
  if (lane == 0) { cnorm[row] = s; cs2[row] = 2.0f * m * (1.0f / 127.0f); }
}

// gate W -> i8 per-row quant; ws[row] = maxabs/127
__global__ void cvt_w_i8(const float* __restrict__ w, u8* __restrict__ wq,
                         float* __restrict__ ws) {
  int row  = blockIdx.x * 4 + (threadIdx.x >> 6);
  int lane = threadIdx.x & 63;
  const float* src = w + (size_t)row * DIM + lane * 8;
  float4 a = *reinterpret_cast<const float4*>(src);
  float4 b = *reinterpret_cast<const float4*>(src + 4);
  float m = fmaxf(fmaxf(fmaxf(fabsf(a.x), fabsf(a.y)), fmaxf(fabsf(a.z), fabsf(a.w))),
                  fmaxf(fmaxf(fabsf(b.x), fabsf(b.y)), fmaxf(fabsf(b.z), fabsf(b.w))));
#pragma unroll
  for (int s = 1; s < 64; s <<= 1) m = fmaxf(m, __shfl_xor(m, s, 64));
  float inv = 127.0f / fmaxf(m, 1e-20f);
  uint2 w2;
  w2.x = pk4(a.x, a.y, a.z, a.w, inv);
  w2.y = pk4(b.x, b.y, b.z, b.w, inv);
  *reinterpret_cast<uint2*>(wq + (size_t)row * DIM + lane * 8) = w2;
  if (lane == 0) ws[row] = m * (1.0f / 127.0f);
}

// --------------- argmin GEMM (i8): score = cnorm - xs*cs2*idot -------------
// R12-verified pipeline: 128x256 tile, BK=64, 8 waves (2M x 4N), counted-vmcnt
// 2-tile-deep. i8 mfma 16x16x64: 16 MFMA + 8 ds_read_b128 per tile (half of
// fp8). b128 frags are bank-uniform with LINEAR layout (l4 spreads 16B slots).
__global__ __launch_bounds__(512, 4)
void argmin_i8(const u8* __restrict__ Xq, const u8* __restrict__ Cq,
               const float* __restrict__ cnorm, const float* __restrict__ cs2,
               const float* __restrict__ xs,
               float* __restrict__ pval, int* __restrict__ pidx) {
  __shared__ __align__(16) u8 As[2][128 * 64];   // 8 KiB each
  __shared__ __align__(16) u8 Bs[2][256 * 64];   // 16 KiB each (48 KiB total)

  const int tid  = threadIdx.x;
  const int lane = tid & 63;
  const int wid  = tid >> 6;          // 0..7
  const int wr   = wid >> 2;          // 0..1 (M half: 64 rows)
  const int wc   = wid & 3;           // 0..3 (N quarter: 64 cols)
  const int bm   = blockIdx.x;        // 0..255 token tiles (128 each)
  const int bn   = blockIdx.y;        // 0..15  code tiles (256 each)
  const int l15  = lane & 15, l4 = lane >> 4;

  const u8* Xg = Xq + (size_t)(bm * 128) * DIM;
  const u8* Cg = Cq + (size_t)(bn * 256) * DIM;

  auto stage = [&](int buf, int kt) {
    int kk = kt * 64;
    {
      int row = wid * 16 + (lane >> 2);            // 0..127
      gload_lds16(Xg + (size_t)row * DIM + kk + (lane & 3) * 16,
                  (void*)(As[buf] + wid * 1024));
    }
#pragma unroll
    for (int p = 0; p < 2; p++) {
      int row = p * 128 + wid * 16 + (lane >> 2);  // 0..255
      gload_lds16(Cg + (size_t)row * DIM + kk + (lane & 3) * 16,
                  (void*)(Bs[buf] + p * 8192 + wid * 1024));
    }
  };

  auto rd16 = [&](const u8* base, int row) -> i32x4 {
    return *reinterpret_cast<const i32x4*>(base + row * 64 + l4 * 16);
  };

  i32x4 acc[4][4];
#pragma unroll
  for (int i = 0; i < 4; i++)
#pragma unroll
    for (int j = 0; j < 4; j++)
#pragma unroll
      for (int r = 0; r < 4; r++) acc[i][j][r] = 0;

  stage(0, 0);
  stage(1, 1);
  asm volatile("s_waitcnt vmcnt(3)" ::: "memory");
  __builtin_amdgcn_s_barrier();
  asm volatile("" ::: "memory");

  for (int t = 0; t < 8; ++t) {
    const u8* A  = As[t & 1];
    const u8* Bt = Bs[t & 1];
    i32x4 bfr[4];
#pragma unroll
    for (int ni = 0; ni < 4; ni++) bfr[ni] = rd16(Bt, wc * 64 + ni * 16 + l15);
#pragma unroll
    for (int mi = 0; mi < 4; mi++) {
      i32x4 af = rd16(A, wr * 64 + mi * 16 + l15);
      __builtin_amdgcn_s_setprio(1);
#pragma unroll
      for (int ni = 0; ni < 4; ni++)
        acc[mi][ni] = __builtin_amdgcn_mfma_i32_16x16x64_i8(
            af, bfr[ni], acc[mi][ni], 0, 0, 0);
      __builtin_amdgcn_s_setprio(0);
    }

    asm volatile("" ::: "memory");
    __builtin_amdgcn_s_barrier();
    asm volatile("" ::: "memory");
    if (t + 2 < 8) {
      stage(t & 1, t + 2);
      asm volatile("s_waitcnt vmcnt(3)" ::: "memory");
      __builtin_amdgcn_s_barrier();
      asm volatile("" ::: "memory");
    } else if (t < 7) {
      asm volatile("s_waitcnt vmcnt(0)" ::: "memory");
      __builtin_amdgcn_s_barrier();
      asm volatile("" ::: "memory");
    }
  }

  // epilogue: per-token argmin over this block's 256 codes
  float* rv = (float*)As;
  int*   ri = (int*)Bs;
  __syncthreads();

  float cn[4], c2[4];
  int   cd[4];
#pragma unroll
  for (int ni = 0; ni < 4; ni++) {
    cd[ni] = bn * 256 + wc * 64 + ni * 16 + l15;
    cn[ni] = cnorm[cd[ni]];
    c2[ni] = cs2[cd[ni]];
  }

#pragma unroll
  for (int mi = 0; mi < 4; mi++) {
#pragma unroll
    for (int r = 0; r < 4; r++) {
      int token = bm * 128 + wr * 64 + mi * 16 + l4 * 4 + r;
      float xsv = xs[token];
      float best = 1e30f;
      int bi = 0;
#pragma unroll
      for (int ni = 0; ni < 4; ni++) {
        float v = cn[ni] - xsv * c2[ni] * (float)acc[mi][ni][r];
        if (v < best) { best = v; bi = cd[ni]; }
      }
#pragma unroll
      for (int m = 1; m < 16; m <<= 1) {
        float ov = __shfl_xor(best, m, 64);
        int   oi = __shfl_xor(bi, m, 64);
        if (ov < best) { best = ov; bi = oi; }
      }
      if (l15 == 0) {
        int tok = wr * 64 + mi * 16 + l4 * 4 + r;
        rv[wc * 128 + tok] = best;
        ri[wc * 128 + tok] = bi;
      }
    }
  }
  __syncthreads();
  if (tid < 128) {
    float bv = rv[tid];
    int   bb = ri[tid];
#pragma unroll
    for (int c = 1; c < 4; c++) {
      float v = rv[c * 128 + tid];
      if (v < bv) { bv = v; bb = ri[c * 128 + tid]; }
    }
    size_t g = (size_t)bn * NTOK + bm * 128 + tid;
    pval[g] = bv;
    pidx[g] = bb;
  }
}

__global__ void argmin_reduce(const float* __restrict__ pval, const int* __restrict__ pidx,
                              int* __restrict__ idx) {
  int t = blockIdx.x * 256 + threadIdx.x;   // 0..32767
  float best = 1e30f;
  int bi = 0;
  for (int c = 0; c < 16; c++) {
    float v = pval[(size_t)c * NTOK + t];
    if (v < best) { best = v; bi = pidx[(size_t)c * NTOK + t]; }
  }
  idx[t] = bi;
}

// -------- gate GEMM (i8, same structure) + fused epilogue + loss -----------
// logit = xs[token]*ws[col]*idot + b[col]; gate precision uncritical (|q|<=2.4e-4)
__global__ __launch_bounds__(512, 4)
void gate_i8(const u8* __restrict__ Xq, const u8* __restrict__ Wq,
             const float* __restrict__ X, const float* __restrict__ Cf,
             const float* __restrict__ gb, const float* __restrict__ xs,
             const float* __restrict__ ws, const int* __restrict__ idx,
             float* __restrict__ out, float* __restrict__ blockSum) {
  __shared__ __align__(16) u8 As[2][128 * 64];
  __shared__ __align__(16) u8 Bs[2][256 * 64];
  __shared__ float bsum[8];

  const int tid  = threadIdx.x;
  const int lane = tid & 63;
  const int wid  = tid >> 6;          // 0..7
  const int wr   = wid >> 2;          // 0..1
  const int wc   = wid & 3;           // 0..3
  const int bm   = blockIdx.x;        // 0..255 token tiles
  const int bn   = blockIdx.y;        // 0..1   col tiles (256 each)
  const int l15  = lane & 15, l4 = lane >> 4;

  const u8* Xg = Xq + (size_t)(bm * 128) * DIM;
  const u8* Wg = Wq + (size_t)(bn * 256) * DIM;

  auto stage = [&](int buf, int kt) {
    int kk = kt * 64;
    {
      int row = wid * 16 + (lane >> 2);
      gload_lds16(Xg + (size_t)row * DIM + kk + (lane & 3) * 16,
                  (void*)(As[buf] + wid * 1024));
    }
#pragma unroll
    for (int p = 0; p < 2; p++) {
      int row = p * 128 + wid * 16 + (lane >> 2);
      gload_lds16(Wg + (size_t)row * DIM + kk + (lane & 3) * 16,
                  (void*)(Bs[buf] + p * 8192 + wid * 1024));
    }
  };

  auto rd16 = [&](const u8* base, int row) -> i32x4 {
    return *reinterpret_cast<const i32x4*>(base + row * 64 + l4 * 16);
  };

  i32x4 acc[4][4];
#pragma unroll
  for (int i = 0; i < 4; i++)
#pragma unroll
    for (int j = 0; j < 4; j++)
#pragma unroll
      for (int r = 0; r < 4; r++) acc[i][j][r] = 0;

  stage(0, 0);
  stage(1, 1);
  asm volatile("s_waitcnt vmcnt(3)" ::: "memory");
  __builtin_amdgcn_s_barrier();
  asm volatile("" ::: "memory");

  for (int t = 0; t < 8; ++t) {
    const u8* A  = As[t & 1];
    const u8* Bt = Bs[t & 1];
    i32x4 bfr[4];
#pragma unroll
    for (int ni = 0; ni < 4; ni++) bfr[ni] = rd16(Bt, wc * 64 + ni * 16 + l15);
#pragma unroll
    for (int mi = 0; mi < 4; mi++) {
      i32x4 af = rd16(A, wr * 64 + mi * 16 + l15);
      __builtin_amdgcn_s_setprio(1);
#pragma unroll
      for (int ni = 0; ni < 4; ni++)
        acc[mi][ni] = __builtin_amdgcn_mfma_i32_16x16x64_i8(
            af, bfr[ni], acc[mi][ni], 0, 0, 0);
      __builtin_amdgcn_s_setprio(0);
    }

    asm volatile("" ::: "memory");
    __builtin_amdgcn_s_barrier();
    asm volatile("" ::: "memory");
    if (t + 2 < 8) {
      stage(t & 1, t + 2);
      asm volatile("s_waitcnt vmcnt(3)" ::: "memory");
      __builtin_amdgcn_s_barrier();
      asm volatile("" ::: "memory");
    } else if (t < 7) {
      asm volatile("s_waitcnt vmcnt(0)" ::: "memory");
      __builtin_amdgcn_s_barrier();
      asm volatile("" ::: "memory");
    }
  }

  // epilogue: gate = sigmoid(xs*ws*idot + b), out = x + c[idx]*gate, loss
  float wsv[4], gbv[4];
  int   cl[4];
#pragma unroll
  for (int ni = 0; ni < 4; ni++) {
    cl[ni] = bn * 256 + wc * 64 + ni * 16 + l15;
    wsv[ni] = ws[cl[ni]];
    gbv[ni] = gb[cl[ni]];
  }
  float lsum = 0.f;
#pragma unroll
  for (int mi = 0; mi < 4; mi++) {
#pragma unroll
    for (int r = 0; r < 4; r++) {
      int token = bm * 128 + wr * 64 + mi * 16 + l4 * 4 + r;
      int code = idx[token];
      float xsv = xs[token];
#pragma unroll
      for (int ni = 0; ni < 4; ni++) {
        int col = cl[ni];
        float logit = xsv * wsv[ni] * (float)acc[mi][ni][r] + gbv[ni];
        float g = 1.0f / (1.0f + __expf(-logit));
        float q = Cf[(size_t)code * DIM + col];
        float xx = X[(size_t)token * DIM + col];
        out[(size_t)token * DIM + col] = xx + q * g;
        float d = q - xx;
        lsum += d * d;
      }
    }
  }
#pragma unroll
  for (int m = 1; m < 64; m <<= 1) lsum += __shfl_xor(lsum, m, 64);
  if (lane == 0) bsum[wid] = lsum;
  __syncthreads();
  if (tid == 0) {
    float s = 0.f;
#pragma unroll
    for (int i = 0; i < 8; i++) s += bsum[i];
    blockSum[blockIdx.y * gridDim.x + blockIdx.x] = s;
  }
}

__global__ void finalize(const float* __restrict__ blockSum, float* __restrict__ out_loss) {
  int t = threadIdx.x;  // 256 threads, 512 partials
  float s = blockSum[t * 2] + blockSum[t * 2 + 1];
#pragma unroll
  for (int m = 1; m < 64; m <<= 1) s += __shfl_xor(s, m, 64);
  __shared__ float w4[4];
  if ((t & 63) == 0) w4[t >> 6] = s;
  __syncthreads();
  if (t == 0) {
    float tot = w4[0] + w4[1] + w4[2] + w4[3];
    out_loss[0] = 1.25f * tot / 16777216.0f;   // N*D = 32768*512
  }
}

extern "C" void kernel_launch(void* const* d_in, const int* in_sizes, int n_in,
                              void* d_out, int out_size, void* d_ws, size_t ws_size,
                              hipStream_t stream) {
  const float* X  = (const float*)d_in[0];   // [32768, 512]
  const float* CB = (const float*)d_in[1];   // [4096, 512]
  const float* GW = (const float*)d_in[2];   // [512, 512]
  const float* GB = (const float*)d_in[3];   // [512]
  float* out = (float*)d_out;                // [32768*512] output + [1] loss

  char* w = (char*)d_ws;
  size_t off = 0;
  auto alloc = [&](size_t bytes) -> void* {
    void* p = w + off;
    off = (off + bytes + 255) & ~(size_t)255;
    return p;
  };
  u8*    Xq    = (u8*) alloc((size_t)NTOK * DIM);       // 16.8 MB (i8, linear)
  u8*    Cq    = (u8*) alloc((size_t)KC * DIM);         // 2.1 MB
  u8*    Wq    = (u8*) alloc((size_t)DIM * DIM);        // 0.25 MB
  float* xsc   = (float*)alloc((size_t)NTOK * 4);       // per-token scale
  float* cnorm = (float*)alloc((size_t)KC * 4);
  float* cs2   = (float*)alloc((size_t)KC * 4);
  float* wsc   = (float*)alloc((size_t)DIM * 4);
  float* pval  = (float*)alloc((size_t)16 * NTOK * 4);  // 2.1 MB
  int*   pidx  = (int*)alloc((size_t)16 * NTOK * 4);    // 2.1 MB
  int*   idx   = (int*)alloc((size_t)NTOK * 4);
  float* bsums = (float*)alloc((size_t)512 * 4);

  cvt_x_i8<<<8192, 256, 0, stream>>>(X, Xq, xsc);
  cvt_cb_i8<<<1024, 256, 0, stream>>>(CB, Cq, cnorm, cs2);
  cvt_w_i8<<<128, 256, 0, stream>>>(GW, Wq, wsc);
  argmin_i8<<<dim3(256, 16), 512, 0, stream>>>(Xq, Cq, cnorm, cs2, xsc, pval, pidx);
  argmin_reduce<<<128, 256, 0, stream>>>(pval, pidx, idx);
  gate_i8<<<dim3(256, 2), 512, 0, stream>>>(Xq, Wq, X, CB, GB, xsc, wsc, idx, out, bsums);
  finalize<<<1, 256, 0, stream>>>(bsums, out + (size_t)NTOK * DIM);
}